// Round 7
// baseline (5302.901 us; speedup 1.0000x reference)
//
#include <hip/hip_runtime.h>
#include <hip/hip_bf16.h>

// Problem constants (from reference)
#define B_    16
#define N_    8192
#define NPOINT 2048
#define K_    16
#define CIN   64
#define COUT  128
#define BN_EPS 1e-5f

// ---------------------------------------------------------------------------
// DPP wave64 max step on a packed u64 key (dist_bits<<32 | (8191-idx)).
// Used for the 16-lane stage-2 reduce (rows of 16).
// ---------------------------------------------------------------------------
template <int CTRL>
__device__ __forceinline__ void keymax_step(unsigned long long& key) {
    int lo = (int)(unsigned)(key & 0xFFFFFFFFull);
    int hi = (int)(unsigned)(key >> 32);
    int olo = __builtin_amdgcn_update_dpp(lo, lo, CTRL, 0xf, 0xf, false);
    int ohi = __builtin_amdgcn_update_dpp(hi, hi, CTRL, 0xf, 0xf, false);
    unsigned long long ok = ((unsigned long long)(unsigned)ohi << 32) |
                            (unsigned long long)(unsigned)olo;
    if (ok > key) key = ok;
}

// f32 DPP max step (compiler folds mov_dpp into v_max_f32).
template <int CTRL>
__device__ __forceinline__ void fmax_step(float& v) {
    int b = __builtin_amdgcn_update_dpp(__builtin_bit_cast(int, v),
                                        __builtin_bit_cast(int, v),
                                        CTRL, 0xf, 0xf, false);
    v = fmaxf(v, __builtin_bit_cast(float, b));
}

// ---------------------------------------------------------------------------
// 1) Farthest point sampling: 1 block (1024 thr, 16 waves = 4/SIMD) per batch.
//    Round-6 lesson: VALUBusy pinned at the 16-CU ceiling -> issue-bound; cut
//    instructions, not latency. Stage-1 wave reduce = f32-only DPP max (6
//    foldable steps) + ballot/ffs/readlane index recovery. Stage-2 = lane-
//    indexed parallel u64 reduce (4 DPP steps in rows of 16) + readlane.
//    Point ownership is LANE-MAJOR (gi = t*8+k) so min-k-within-lane and
//    min-lane-among-ties are both min-global-index (exact numpy argmax ties).
//    Bit-exact numpy arithmetic: ((dx*dx+dy*dy)+dz*dz) via _rn intrinsics.
// ---------------------------------------------------------------------------
__global__ __launch_bounds__(1024, 1) void fps_kernel(const float* __restrict__ xyz,
                                                      int* __restrict__ fps_idx,
                                                      float* __restrict__ out_xyz) {
    const int b = blockIdx.x;
    const int t = threadIdx.x;            // 0..1023
    const float* P = xyz + (size_t)b * N_ * 3;

    __shared__ float sx[N_], sy[N_], sz[N_];          // 96 KiB SoA
    __shared__ int   s_idx[NPOINT];                    // 8 KiB winner journal
    __shared__ __align__(16) unsigned long long s_key[2][16];

    for (int j = t; j < N_; j += 1024) {
        sx[j] = P[j * 3 + 0];
        sy[j] = P[j * 3 + 1];
        sz[j] = P[j * 3 + 2];
    }
    if (t == 0) s_idx[0] = 0;
    __syncthreads();

    // lane-major ownership: thread t owns points [t*8, t*8+8)
    float px[8], py[8], pz[8], dist[8];
#pragma unroll
    for (int k = 0; k < 8; ++k) {
        int gi = t * 8 + k;
        px[k] = sx[gi];
        py[k] = sy[gi];
        pz[k] = sz[gi];
        dist[k] = 1e10f;
    }

    int cur = 0;      // current farthest (centroid) index, uniform across block
    int buf = 0;
    const int wv_id = t >> 6;             // 0..15
    const int lane  = t & 63;

    for (int it = 1; it < NPOINT; ++it) {
        // centroid: broadcast LDS reads (uniform address)
        float cx = sx[cur], cy = sy[cur], cz = sz[cur];

        float bv = -1.0f; int bk = 0;
#pragma unroll
        for (int k = 0; k < 8; ++k) {
            float dx = __fsub_rn(px[k], cx);
            float dy = __fsub_rn(py[k], cy);
            float dz = __fsub_rn(pz[k], cz);
            float d  = __fadd_rn(__fadd_rn(__fmul_rn(dx, dx), __fmul_rn(dy, dy)),
                                 __fmul_rn(dz, dz));
            float nd = fminf(dist[k], d);
            dist[k] = nd;
            // ascending k => ascending global index; strict > keeps lowest idx
            if (nd > bv) { bv = nd; bk = k; }
        }

        // stage 1: wave max VALUE via 6 DPP f32-max steps (lane 63 holds max)
        float m = bv;
        fmax_step<0x111>(m);   // row_shr:1
        fmax_step<0x112>(m);   // row_shr:2
        fmax_step<0x114>(m);   // row_shr:4
        fmax_step<0x118>(m);   // row_shr:8
        fmax_step<0x142>(m);   // row_bcast:15
        fmax_step<0x143>(m);   // row_bcast:31
        float M = __builtin_bit_cast(float,
                    __builtin_amdgcn_readlane(__builtin_bit_cast(int, m), 63));

        // index recovery: lowest tied lane (lane-major => lowest global idx)
        unsigned long long tied = __ballot(bv == M);
        int L   = __ffsll((long long)tied) - 1;
        int bkL = __builtin_amdgcn_readlane(bk, L);
        int gi  = ((wv_id << 6) + L) * 8 + bkL;     // uniform within wave

        // publish packed key (all-uniform; one lane writes)
        unsigned long long key =
            ((unsigned long long)__float_as_uint(M) << 32) |
            (unsigned long long)(unsigned)(N_ - 1 - gi);
        if (lane == 0) s_key[buf][wv_id] = key;
        __syncthreads();

        // stage 2: lane-indexed parallel reduce of the 16 wave keys
        unsigned long long k2 = s_key[buf][t & 15];
        keymax_step<0x111>(k2);   // row_shr:1  (within rows of 16)
        keymax_step<0x112>(k2);   // row_shr:2
        keymax_step<0x114>(k2);   // row_shr:4
        keymax_step<0x118>(k2);   // row_shr:8
        int lo15 = __builtin_amdgcn_readlane((int)(unsigned)(k2 & 0xFFFFFFFFull), 15);
        cur = N_ - 1 - lo15;
        if (t == 0) s_idx[it] = cur;    // LDS journal only
        buf ^= 1;
    }

    __syncthreads();
    // epilogue: flush fps_idx + fused new_xyz gather (coords are in LDS)
    int* dst = fps_idx + b * NPOINT;
    float* oxyz = out_xyz + (size_t)b * NPOINT * 3;
    for (int q = t; q < NPOINT; q += 1024) {
        int idx = s_idx[q];
        dst[q] = idx;
        oxyz[q * 3 + 0] = sx[idx];
        oxyz[q * 3 + 1] = sy[idx];
        oxyz[q * 3 + 2] = sz[idx];
    }
}

// ---------------------------------------------------------------------------
// 2) kNN, 4-way segmented: block = 256 thr = 64 queries x 4 segments (wave =
//    one segment of 64 queries). Each thread scans its 2048-point segment via
//    1024-pt LDS tiles, keeps sorted top-16 (strict <, first-index ties).
//    Final stable 4-way merge (segment-priority on ties) == full ascending
//    scan's top-16 set. LDS: tiles (48 KB) overlaid with merge lists (32 KB).
// ---------------------------------------------------------------------------
#define KT 1024
__global__ __launch_bounds__(256, 3) void knn_kernel(const float* __restrict__ xyz,
                                                     const int* __restrict__ fps_idx,
                                                     int* __restrict__ knn_idx) {
    const int b = blockIdx.y;
    const int ql = threadIdx.x & 63;      // query slot in block
    const int seg = threadIdx.x >> 6;     // 0..3 == wave id
    const int q = blockIdx.x * 64 + ql;   // 0..2047
    const float* P = xyz + (size_t)b * N_ * 3;
    const int qi = fps_idx[b * NPOINT + q];
    const float qx = P[qi * 3 + 0], qy = P[qi * 3 + 1], qz = P[qi * 3 + 2];

    __shared__ __align__(16) char smem[49152];      // 48 KB
    float* sx = (float*)smem;                        // [4096] tiles (4 segs x KT)
    float* sy = sx + 4096;
    float* sz = sy + 4096;
    float* md = (float*)smem;                        // merge dists  [64*4*16]
    int*   mi = (int*)smem + 4096;                   // merge indices [64*4*16]

    float bd[K_]; int bix[K_];
#pragma unroll
    for (int j = 0; j < K_; ++j) { bd[j] = 3.4e38f; bix[j] = 0; }

    const int segbase = seg << 11;        // seg * 2048

    for (int tile = 0; tile < 2048; tile += KT) {
        for (int j = threadIdx.x; j < 4 * KT; j += 256) {
            int s2 = j >> 10, i = j & (KT - 1);
            int g = (s2 << 11) + tile + i;
            sx[j] = P[g * 3 + 0];
            sy[j] = P[g * 3 + 1];
            sz[j] = P[g * 3 + 2];
        }
        __syncthreads();
        const float* tsx = sx + (seg << 10);
        const float* tsy = sy + (seg << 10);
        const float* tsz = sz + (seg << 10);
        const int gbase = segbase + tile;
#pragma unroll 4
        for (int i = 0; i < KT; ++i) {
            float dx = __fsub_rn(qx, tsx[i]);
            float dy = __fsub_rn(qy, tsy[i]);
            float dz = __fsub_rn(qz, tsz[i]);
            float d  = __fadd_rn(__fadd_rn(__fmul_rn(dx, dx), __fmul_rn(dy, dy)),
                                 __fmul_rn(dz, dz));
            if (d < bd[K_ - 1]) {          // strict: equal distances keep earlier idx
                bd[K_ - 1] = d; bix[K_ - 1] = gbase + i;
#pragma unroll
                for (int j = K_ - 1; j > 0; --j) {
                    if (bd[j] < bd[j - 1]) {
                        float tv = bd[j]; bd[j] = bd[j - 1]; bd[j - 1] = tv;
                        int   ti = bix[j]; bix[j] = bix[j - 1]; bix[j - 1] = ti;
                    }
                }
            }
        }
        __syncthreads();
    }

    // publish per-segment sorted lists, then wave 0 merges (stable by segment)
    const int o = ql << 6;                // ql * 64 entries
#pragma unroll
    for (int j = 0; j < K_; ++j) {
        md[o + (seg << 4) + j] = bd[j];
        mi[o + (seg << 4) + j] = bix[j];
    }
    __syncthreads();
    if (seg == 0) {
        int p0 = 0, p1 = 0, p2 = 0, p3 = 0;
        int* dst = knn_idx + ((size_t)b * NPOINT + q) * K_;
#pragma unroll
        for (int j = 0; j < K_; ++j) {
            float v0 = md[o + p0];
            float v1 = md[o + 16 + p1];
            float v2 = md[o + 32 + p2];
            float v3 = md[o + 48 + p3];
            float v = v0; int s = 0;
            if (v1 < v) { v = v1; s = 1; }   // strict: ties prefer lower segment
            if (v2 < v) { v = v2; s = 2; }
            if (v3 < v) { v = v3; s = 3; }
            int pos = (s == 0) ? p0 : ((s == 1) ? p1 : ((s == 2) ? p2 : p3));
            dst[j] = mi[o + (s << 4) + pos];
            p0 += (s == 0); p1 += (s == 1); p2 += (s == 2); p3 += (s == 3);
        }
    }
}

// ---------------------------------------------------------------------------
// 3) 1x1 conv GEMM: h[131072,128] = feat[131072,64] @ W^T + b, fp32 vector.
//    Block = 64 rows x 128 cols tile. Also emits per-block channel sum/sumsq.
// ---------------------------------------------------------------------------
__global__ __launch_bounds__(256) void gemm_kernel(const float* __restrict__ feat,
                                                   const float* __restrict__ W,
                                                   const float* __restrict__ bias,
                                                   float* __restrict__ h,
                                                   float* __restrict__ partials) {
    __shared__ float wT[64 * 132];      // wT[c*132 + o]
    __shared__ float fT[64 * 68];       // fT[c*68 + r]
    __shared__ float redsum[COUT], redsq[COUT];
    const int tid = threadIdx.x;
    const size_t row0 = (size_t)blockIdx.x * 64;

    for (int g = tid; g < COUT * CIN; g += 256) {
        int o = g >> 6, c = g & 63;
        wT[c * 132 + o] = W[g];
    }
    for (int g = tid; g < 64 * CIN; g += 256) {
        int r = g >> 6, c = g & 63;
        fT[c * 68 + r] = feat[(row0 + r) * CIN + c];
    }
    if (tid < COUT) { redsum[tid] = 0.f; redsq[tid] = 0.f; }
    __syncthreads();

    const int rbase = (tid >> 4) * 4;   // 0..60, multiple of 4 -> 16B aligned
    const int cbase = (tid & 15) * 8;   // 0..120, multiple of 8 -> 16B aligned

    float acc[4][8];
#pragma unroll
    for (int r = 0; r < 4; ++r)
#pragma unroll
        for (int j = 0; j < 8; ++j) acc[r][j] = bias[cbase + j];

    for (int c = 0; c < CIN; ++c) {
        const float4 f  = *(const float4*)(fT + c * 68 + rbase);    // ds_read_b128
        const float4 w0 = *(const float4*)(wT + c * 132 + cbase);   // ds_read_b128
        const float4 w1 = *(const float4*)(wT + c * 132 + cbase + 4);
        float wv[8] = {w0.x, w0.y, w0.z, w0.w, w1.x, w1.y, w1.z, w1.w};
#pragma unroll
        for (int j = 0; j < 8; ++j) {
            acc[0][j] = fmaf(f.x, wv[j], acc[0][j]);
            acc[1][j] = fmaf(f.y, wv[j], acc[1][j]);
            acc[2][j] = fmaf(f.z, wv[j], acc[2][j]);
            acc[3][j] = fmaf(f.w, wv[j], acc[3][j]);
        }
    }

    float psum[8], psq[8];
#pragma unroll
    for (int j = 0; j < 8; ++j) { psum[j] = 0.f; psq[j] = 0.f; }
#pragma unroll
    for (int r = 0; r < 4; ++r) {
        float4 v0 = make_float4(acc[r][0], acc[r][1], acc[r][2], acc[r][3]);
        float4 v1 = make_float4(acc[r][4], acc[r][5], acc[r][6], acc[r][7]);
        float4* dst = (float4*)(h + (row0 + rbase + r) * COUT + cbase);
        dst[0] = v0; dst[1] = v1;
#pragma unroll
        for (int j = 0; j < 8; ++j) {
            psum[j] += acc[r][j];
            psq[j]  += acc[r][j] * acc[r][j];
        }
    }
#pragma unroll
    for (int j = 0; j < 8; ++j) {
        atomicAdd(&redsum[cbase + j], psum[j]);
        atomicAdd(&redsq[cbase + j], psq[j]);
    }
    __syncthreads();
    if (tid < COUT) {
        partials[(size_t)blockIdx.x * 256 + tid] = redsum[tid];
        partials[(size_t)blockIdx.x * 256 + COUT + tid] = redsq[tid];
    }
}

// ---------------------------------------------------------------------------
// 4) BN finalize: parallel deterministic reduction, 1 block per channel.
// ---------------------------------------------------------------------------
__global__ __launch_bounds__(256) void bn_finalize_kernel(const float* __restrict__ partials,
                                                          const float* __restrict__ gamma,
                                                          const float* __restrict__ beta,
                                                          float* __restrict__ stats) {
    const int c = blockIdx.x;             // 0..127
    const int t = threadIdx.x;            // 0..255
    float s = 0.f, sq = 0.f;
    for (int blk = t; blk < 2048; blk += 256) {
        s  += partials[(size_t)blk * 256 + c];
        sq += partials[(size_t)blk * 256 + COUT + c];
    }
    __shared__ float rs[256], rq[256];
    rs[t] = s; rq[t] = sq;
    __syncthreads();
    for (int off = 128; off > 0; off >>= 1) {
        if (t < off) { rs[t] += rs[t + off]; rq[t] += rq[t + off]; }
        __syncthreads();
    }
    if (t == 0) {
        const float invn = 1.0f / (float)(B_ * N_);
        float mean = rs[0] * invn;
        float var  = rq[0] * invn - mean * mean;
        float scale = gamma[c] / sqrtf(var + BN_EPS);
        float shift = beta[c] - mean * scale;
        stats[c] = scale;
        stats[COUT + c] = shift;
    }
}

// ---------------------------------------------------------------------------
// 5) Gather K neighbors, fused BN affine + ReLU, max-pool over K.
//    Block = 8 queries x 32 lanes, float4 per lane (16B/lane coalesced).
// ---------------------------------------------------------------------------
__global__ __launch_bounds__(256) void gather_max_kernel(const float* __restrict__ h,
                                                         const int* __restrict__ knn_idx,
                                                         const float* __restrict__ stats,
                                                         float* __restrict__ out) {
    const int lane = threadIdx.x & 31;
    const int qq = blockIdx.x * 8 + (threadIdx.x >> 5);  // global query [0, 32768)
    const int b = qq >> 11;
    const int c4 = lane * 4;
    const int* idx = knn_idx + (size_t)qq * K_;
    const float4 scale = *(const float4*)(stats + c4);
    const float4 shift = *(const float4*)(stats + COUT + c4);
    const float* hb = h + (size_t)b * N_ * COUT;
    float4 m = make_float4(-3.4e38f, -3.4e38f, -3.4e38f, -3.4e38f);
#pragma unroll
    for (int k = 0; k < K_; ++k) {
        const float4 v = *(const float4*)(hb + (size_t)idx[k] * COUT + c4);
        m.x = fmaxf(m.x, fmaxf(fmaf(v.x, scale.x, shift.x), 0.f));
        m.y = fmaxf(m.y, fmaxf(fmaf(v.y, scale.y, shift.y), 0.f));
        m.z = fmaxf(m.z, fmaxf(fmaf(v.z, scale.z, shift.z), 0.f));
        m.w = fmaxf(m.w, fmaxf(fmaf(v.w, scale.w, shift.w), 0.f));
    }
    *(float4*)(out + B_ * NPOINT * 3 + (size_t)qq * COUT + c4) = m;
}

// ---------------------------------------------------------------------------
extern "C" void kernel_launch(void* const* d_in, const int* in_sizes, int n_in,
                              void* d_out, int out_size, void* d_ws, size_t ws_size,
                              hipStream_t stream) {
    const float* xyz   = (const float*)d_in[0];  // [16,8192,3]
    const float* feat  = (const float*)d_in[1];  // [16,8192,64]
    const float* W     = (const float*)d_in[2];  // [128,64]
    const float* bias  = (const float*)d_in[3];  // [128]
    const float* gamma = (const float*)d_in[4];  // [128]
    const float* beta  = (const float*)d_in[5];  // [128]
    float* out = (float*)d_out;

    // workspace carving (all 256B-aligned by construction)
    char* ws = (char*)d_ws;
    int*   fps_idx  = (int*)(ws);                          // 16*2048*4        = 131072 B
    int*   knn_idx  = (int*)(ws + 131072);                 // 16*2048*16*4     = 2097152 B
    float* partials = (float*)(ws + 131072 + 2097152);     // 2048*256*4       = 2097152 B
    float* stats    = (float*)(ws + 131072 + 2097152 + 2097152);        // 256*4 = 1024 B
    float* h        = (float*)(ws + 131072 + 2097152 + 2097152 + 1024); // 16*8192*128*4 = 64 MiB

    fps_kernel<<<B_, 1024, 0, stream>>>(xyz, fps_idx, out);   // also writes new_xyz
    // DIAGNOSTIC (round 7): knn launched twice into the SAME buffer
    // (idempotent). Total-time delta vs round 6 isolates knn's true cost,
    // testing the "tail is mostly fixed harness overhead" hypothesis.
    knn_kernel<<<dim3(NPOINT / 64, B_), 256, 0, stream>>>(xyz, fps_idx, knn_idx);
    knn_kernel<<<dim3(NPOINT / 64, B_), 256, 0, stream>>>(xyz, fps_idx, knn_idx);
    gemm_kernel<<<(B_ * N_) / 64, 256, 0, stream>>>(feat, W, bias, h, partials);
    bn_finalize_kernel<<<COUT, 256, 0, stream>>>(partials, gamma, beta, stats);
    gather_max_kernel<<<(B_ * NPOINT) / 8, 256, 0, stream>>>(h, knn_idx, stats, out);
}

// Round 8
// 2574.394 us; speedup vs baseline: 2.0599x; 2.0599x over previous
//
#include <hip/hip_runtime.h>
#include <hip/hip_bf16.h>

// Problem constants (from reference)
#define B_    16
#define N_    8192
#define NPOINT 2048
#define K_    16
#define CIN   64
#define COUT  128
#define BN_EPS 1e-5f

// ---------------------------------------------------------------------------
// DPP wave64 max step on a packed u64 key. Used by fps stage-2 (rows of 16).
// ---------------------------------------------------------------------------
template <int CTRL>
__device__ __forceinline__ void keymax_step(unsigned long long& key) {
    int lo = (int)(unsigned)(key & 0xFFFFFFFFull);
    int hi = (int)(unsigned)(key >> 32);
    int olo = __builtin_amdgcn_update_dpp(lo, lo, CTRL, 0xf, 0xf, false);
    int ohi = __builtin_amdgcn_update_dpp(hi, hi, CTRL, 0xf, 0xf, false);
    unsigned long long ok = ((unsigned long long)(unsigned)ohi << 32) |
                            (unsigned long long)(unsigned)olo;
    if (ok > key) key = ok;
}

// f32 DPP max step (compiler folds mov_dpp into v_max_f32).
template <int CTRL>
__device__ __forceinline__ void fmax_step(float& v) {
    int b = __builtin_amdgcn_update_dpp(__builtin_bit_cast(int, v),
                                        __builtin_bit_cast(int, v),
                                        CTRL, 0xf, 0xf, false);
    v = fmaxf(v, __builtin_bit_cast(float, b));
}

// ---------------------------------------------------------------------------
// 1) Farthest point sampling: 1 block (1024 thr, 16 waves = 4/SIMD) per batch.
//    Issue-bound at ~92% of the 16-CU VALU ceiling (round 7) -- kept as-is.
//    Stage-1 wave reduce = f32 DPP max + ballot/ffs/readlane index recovery;
//    stage-2 = lane-indexed u64 DPP reduce of the 16 wave keys. Lane-major
//    point ownership (gi = t*8+k) makes all tie-breaks min-global-index.
//    Bit-exact numpy arithmetic: ((dx*dx+dy*dy)+dz*dz) via _rn intrinsics.
// ---------------------------------------------------------------------------
__global__ __launch_bounds__(1024, 1) void fps_kernel(const float* __restrict__ xyz,
                                                      int* __restrict__ fps_idx,
                                                      float* __restrict__ out_xyz) {
    const int b = blockIdx.x;
    const int t = threadIdx.x;            // 0..1023
    const float* P = xyz + (size_t)b * N_ * 3;

    __shared__ float sx[N_], sy[N_], sz[N_];          // 96 KiB SoA
    __shared__ int   s_idx[NPOINT];                    // 8 KiB winner journal
    __shared__ __align__(16) unsigned long long s_key[2][16];

    for (int j = t; j < N_; j += 1024) {
        sx[j] = P[j * 3 + 0];
        sy[j] = P[j * 3 + 1];
        sz[j] = P[j * 3 + 2];
    }
    if (t == 0) s_idx[0] = 0;
    __syncthreads();

    // lane-major ownership: thread t owns points [t*8, t*8+8)
    float px[8], py[8], pz[8], dist[8];
#pragma unroll
    for (int k = 0; k < 8; ++k) {
        int gi = t * 8 + k;
        px[k] = sx[gi];
        py[k] = sy[gi];
        pz[k] = sz[gi];
        dist[k] = 1e10f;
    }

    int cur = 0;      // current farthest (centroid) index, uniform across block
    int buf = 0;
    const int wv_id = t >> 6;             // 0..15
    const int lane  = t & 63;

    for (int it = 1; it < NPOINT; ++it) {
        // centroid: broadcast LDS reads (uniform address)
        float cx = sx[cur], cy = sy[cur], cz = sz[cur];

        float bv = -1.0f; int bk = 0;
#pragma unroll
        for (int k = 0; k < 8; ++k) {
            float dx = __fsub_rn(px[k], cx);
            float dy = __fsub_rn(py[k], cy);
            float dz = __fsub_rn(pz[k], cz);
            float d  = __fadd_rn(__fadd_rn(__fmul_rn(dx, dx), __fmul_rn(dy, dy)),
                                 __fmul_rn(dz, dz));
            float nd = fminf(dist[k], d);
            dist[k] = nd;
            // ascending k => ascending global index; strict > keeps lowest idx
            if (nd > bv) { bv = nd; bk = k; }
        }

        // stage 1: wave max VALUE via 6 DPP f32-max steps (lane 63 holds max)
        float m = bv;
        fmax_step<0x111>(m);   // row_shr:1
        fmax_step<0x112>(m);   // row_shr:2
        fmax_step<0x114>(m);   // row_shr:4
        fmax_step<0x118>(m);   // row_shr:8
        fmax_step<0x142>(m);   // row_bcast:15
        fmax_step<0x143>(m);   // row_bcast:31
        float M = __builtin_bit_cast(float,
                    __builtin_amdgcn_readlane(__builtin_bit_cast(int, m), 63));

        // index recovery: lowest tied lane (lane-major => lowest global idx)
        unsigned long long tied = __ballot(bv == M);
        int L   = __ffsll((long long)tied) - 1;
        int bkL = __builtin_amdgcn_readlane(bk, L);
        int gi  = ((wv_id << 6) + L) * 8 + bkL;     // uniform within wave

        // publish packed key (all-uniform; one lane writes)
        unsigned long long key =
            ((unsigned long long)__float_as_uint(M) << 32) |
            (unsigned long long)(unsigned)(N_ - 1 - gi);
        if (lane == 0) s_key[buf][wv_id] = key;
        __syncthreads();

        // stage 2: lane-indexed parallel reduce of the 16 wave keys
        unsigned long long k2 = s_key[buf][t & 15];
        keymax_step<0x111>(k2);   // row_shr:1  (within rows of 16)
        keymax_step<0x112>(k2);   // row_shr:2
        keymax_step<0x114>(k2);   // row_shr:4
        keymax_step<0x118>(k2);   // row_shr:8
        int lo15 = __builtin_amdgcn_readlane((int)(unsigned)(k2 & 0xFFFFFFFFull), 15);
        cur = N_ - 1 - lo15;
        if (t == 0) s_idx[it] = cur;    // LDS journal only
        buf ^= 1;
    }

    __syncthreads();
    // epilogue: flush fps_idx + fused new_xyz gather (coords are in LDS)
    int* dst = fps_idx + b * NPOINT;
    float* oxyz = out_xyz + (size_t)b * NPOINT * 3;
    for (int q = t; q < NPOINT; q += 1024) {
        int idx = s_idx[q];
        dst[q] = idx;
        oxyz[q * 3 + 0] = sx[idx];
        oxyz[q * 3 + 1] = sy[idx];
        oxyz[q * 3 + 2] = sz[idx];
    }
}

// ---------------------------------------------------------------------------
// 2) kNN, wave-cooperative: 1 wave per query (16 queries / 1024-thr block).
//    Round-7 lesson: thread-per-query top-K pays the 64-lane union of insert
//    probabilities (~85% of iterations run the 90-VALU shift chain). Here the
//    64 lanes of a wave compute 64 distances per step; the top-16 lives as a
//    sorted u64 key list (dist_bits<<32 | idx), ONE ELEMENT PER LANE in each
//    row of 16. Candidates (d < T, T = 16th-best dist) are rare (~116/query);
//    each insert is a branchless DPP shift + 2 selects. Scan in index order
//    + strict < reproduces numpy top_k tie-breaks exactly (later idx loses).
//    Bit-exact numpy arithmetic: ((dx*dx+dy*dy)+dz*dz) via _rn intrinsics.
// ---------------------------------------------------------------------------
__global__ __launch_bounds__(1024, 1) void knn_kernel(const float* __restrict__ xyz,
                                                      const int* __restrict__ fps_idx,
                                                      int* __restrict__ knn_idx) {
    const int b = blockIdx.y;
    const int wv = threadIdx.x >> 6;      // 0..15
    const int lane = threadIdx.x & 63;
    const int q = blockIdx.x * 16 + wv;   // 0..2047
    const float* P = xyz + (size_t)b * N_ * 3;

    __shared__ float sx[N_], sy[N_], sz[N_];          // 96 KiB SoA
    for (int j = threadIdx.x; j < N_; j += 1024) {
        sx[j] = P[j * 3 + 0];
        sy[j] = P[j * 3 + 1];
        sz[j] = P[j * 3 + 2];
    }
    __syncthreads();

    const int qi = fps_idx[b * NPOINT + q];           // wave-uniform
    const float qx = sx[qi], qy = sy[qi], qz = sz[qi]; // broadcast LDS reads

    // sorted ascending top-16 keys, one per lane within each row of 16
    // (all 4 rows hold identical copies). init = (+inf dist, idx all-ones).
    unsigned long long key = 0x7F800000FFFFFFFFull;
    float T = __builtin_bit_cast(float, 0x7F800000u);  // +inf

    for (int t = 0; t < N_ / 64; ++t) {
        const int i = (t << 6) + lane;
        float dx = __fsub_rn(qx, sx[i]);
        float dy = __fsub_rn(qy, sy[i]);
        float dz = __fsub_rn(qz, sz[i]);
        float d  = __fadd_rn(__fadd_rn(__fmul_rn(dx, dx), __fmul_rn(dy, dy)),
                             __fmul_rn(dz, dz));

        unsigned long long rem = __ballot(d < T);
        while (rem) {
            int L = __ffsll((long long)rem) - 1;
            unsigned cd = (unsigned)__builtin_amdgcn_readlane(
                              __builtin_bit_cast(int, d), L);
            unsigned long long c =
                ((unsigned long long)cd << 32) | (unsigned)((t << 6) + L);

            // branchless sorted insert within rows of 16:
            // m_j = key_{j-1} (row_shr:1, bound_ctrl=true -> lane0 gets 0,
            // and u64 0 is the minimum key). k' = key<=c ? key
            //                                          : (m<=c ? c : m)
            int klo = (int)(unsigned)(key & 0xFFFFFFFFull);
            int khi = (int)(unsigned)(key >> 32);
            int mlo = __builtin_amdgcn_update_dpp(0, klo, 0x111, 0xf, 0xf, true);
            int mhi = __builtin_amdgcn_update_dpp(0, khi, 0x111, 0xf, 0xf, true);
            unsigned long long m =
                ((unsigned long long)(unsigned)mhi << 32) | (unsigned)(unsigned)mlo;
            unsigned long long t1 = (m <= c) ? c : m;
            key = (key <= c) ? key : t1;

            // new threshold = dist field of lane 15's key
            int nhi = __builtin_amdgcn_readlane((int)(unsigned)(key >> 32), 15);
            T = __builtin_bit_cast(float, nhi);

            rem &= rem - 1;                 // drop processed lane
            rem &= __ballot(d < T);         // prune now-failing candidates
        }
    }

    if (lane < K_) {
        knn_idx[((size_t)b * NPOINT + q) * K_ + lane] =
            (int)(unsigned)(key & 0xFFFFFFFFull);
    }
}

// ---------------------------------------------------------------------------
// 3) 1x1 conv GEMM: h[131072,128] = feat[131072,64] @ W^T + b, fp32 vector.
//    Block = 64 rows x 128 cols tile. Also emits per-block channel sum/sumsq.
// ---------------------------------------------------------------------------
__global__ __launch_bounds__(256) void gemm_kernel(const float* __restrict__ feat,
                                                   const float* __restrict__ W,
                                                   const float* __restrict__ bias,
                                                   float* __restrict__ h,
                                                   float* __restrict__ partials) {
    __shared__ float wT[64 * 132];      // wT[c*132 + o]
    __shared__ float fT[64 * 68];       // fT[c*68 + r]
    __shared__ float redsum[COUT], redsq[COUT];
    const int tid = threadIdx.x;
    const size_t row0 = (size_t)blockIdx.x * 64;

    for (int g = tid; g < COUT * CIN; g += 256) {
        int o = g >> 6, c = g & 63;
        wT[c * 132 + o] = W[g];
    }
    for (int g = tid; g < 64 * CIN; g += 256) {
        int r = g >> 6, c = g & 63;
        fT[c * 68 + r] = feat[(row0 + r) * CIN + c];
    }
    if (tid < COUT) { redsum[tid] = 0.f; redsq[tid] = 0.f; }
    __syncthreads();

    const int rbase = (tid >> 4) * 4;   // 0..60, multiple of 4 -> 16B aligned
    const int cbase = (tid & 15) * 8;   // 0..120, multiple of 8 -> 16B aligned

    float acc[4][8];
#pragma unroll
    for (int r = 0; r < 4; ++r)
#pragma unroll
        for (int j = 0; j < 8; ++j) acc[r][j] = bias[cbase + j];

    for (int c = 0; c < CIN; ++c) {
        const float4 f  = *(const float4*)(fT + c * 68 + rbase);    // ds_read_b128
        const float4 w0 = *(const float4*)(wT + c * 132 + cbase);   // ds_read_b128
        const float4 w1 = *(const float4*)(wT + c * 132 + cbase + 4);
        float wv[8] = {w0.x, w0.y, w0.z, w0.w, w1.x, w1.y, w1.z, w1.w};
#pragma unroll
        for (int j = 0; j < 8; ++j) {
            acc[0][j] = fmaf(f.x, wv[j], acc[0][j]);
            acc[1][j] = fmaf(f.y, wv[j], acc[1][j]);
            acc[2][j] = fmaf(f.z, wv[j], acc[2][j]);
            acc[3][j] = fmaf(f.w, wv[j], acc[3][j]);
        }
    }

    float psum[8], psq[8];
#pragma unroll
    for (int j = 0; j < 8; ++j) { psum[j] = 0.f; psq[j] = 0.f; }
#pragma unroll
    for (int r = 0; r < 4; ++r) {
        float4 v0 = make_float4(acc[r][0], acc[r][1], acc[r][2], acc[r][3]);
        float4 v1 = make_float4(acc[r][4], acc[r][5], acc[r][6], acc[r][7]);
        float4* dst = (float4*)(h + (row0 + rbase + r) * COUT + cbase);
        dst[0] = v0; dst[1] = v1;
#pragma unroll
        for (int j = 0; j < 8; ++j) {
            psum[j] += acc[r][j];
            psq[j]  += acc[r][j] * acc[r][j];
        }
    }
#pragma unroll
    for (int j = 0; j < 8; ++j) {
        atomicAdd(&redsum[cbase + j], psum[j]);
        atomicAdd(&redsq[cbase + j], psq[j]);
    }
    __syncthreads();
    if (tid < COUT) {
        partials[(size_t)blockIdx.x * 256 + tid] = redsum[tid];
        partials[(size_t)blockIdx.x * 256 + COUT + tid] = redsq[tid];
    }
}

// ---------------------------------------------------------------------------
// 4) BN finalize: parallel deterministic reduction, 1 block per channel.
// ---------------------------------------------------------------------------
__global__ __launch_bounds__(256) void bn_finalize_kernel(const float* __restrict__ partials,
                                                          const float* __restrict__ gamma,
                                                          const float* __restrict__ beta,
                                                          float* __restrict__ stats) {
    const int c = blockIdx.x;             // 0..127
    const int t = threadIdx.x;            // 0..255
    float s = 0.f, sq = 0.f;
    for (int blk = t; blk < 2048; blk += 256) {
        s  += partials[(size_t)blk * 256 + c];
        sq += partials[(size_t)blk * 256 + COUT + c];
    }
    __shared__ float rs[256], rq[256];
    rs[t] = s; rq[t] = sq;
    __syncthreads();
    for (int off = 128; off > 0; off >>= 1) {
        if (t < off) { rs[t] += rs[t + off]; rq[t] += rq[t + off]; }
        __syncthreads();
    }
    if (t == 0) {
        const float invn = 1.0f / (float)(B_ * N_);
        float mean = rs[0] * invn;
        float var  = rq[0] * invn - mean * mean;
        float scale = gamma[c] / sqrtf(var + BN_EPS);
        float shift = beta[c] - mean * scale;
        stats[c] = scale;
        stats[COUT + c] = shift;
    }
}

// ---------------------------------------------------------------------------
// 5) Gather K neighbors, fused BN affine + ReLU, max-pool over K.
//    Block = 8 queries x 32 lanes, float4 per lane (16B/lane coalesced).
// ---------------------------------------------------------------------------
__global__ __launch_bounds__(256) void gather_max_kernel(const float* __restrict__ h,
                                                         const int* __restrict__ knn_idx,
                                                         const float* __restrict__ stats,
                                                         float* __restrict__ out) {
    const int lane = threadIdx.x & 31;
    const int qq = blockIdx.x * 8 + (threadIdx.x >> 5);  // global query [0, 32768)
    const int b = qq >> 11;
    const int c4 = lane * 4;
    const int* idx = knn_idx + (size_t)qq * K_;
    const float4 scale = *(const float4*)(stats + c4);
    const float4 shift = *(const float4*)(stats + COUT + c4);
    const float* hb = h + (size_t)b * N_ * COUT;
    float4 m = make_float4(-3.4e38f, -3.4e38f, -3.4e38f, -3.4e38f);
#pragma unroll
    for (int k = 0; k < K_; ++k) {
        const float4 v = *(const float4*)(hb + (size_t)idx[k] * COUT + c4);
        m.x = fmaxf(m.x, fmaxf(fmaf(v.x, scale.x, shift.x), 0.f));
        m.y = fmaxf(m.y, fmaxf(fmaf(v.y, scale.y, shift.y), 0.f));
        m.z = fmaxf(m.z, fmaxf(fmaf(v.z, scale.z, shift.z), 0.f));
        m.w = fmaxf(m.w, fmaxf(fmaf(v.w, scale.w, shift.w), 0.f));
    }
    *(float4*)(out + B_ * NPOINT * 3 + (size_t)qq * COUT + c4) = m;
}

// ---------------------------------------------------------------------------
extern "C" void kernel_launch(void* const* d_in, const int* in_sizes, int n_in,
                              void* d_out, int out_size, void* d_ws, size_t ws_size,
                              hipStream_t stream) {
    const float* xyz   = (const float*)d_in[0];  // [16,8192,3]
    const float* feat  = (const float*)d_in[1];  // [16,8192,64]
    const float* W     = (const float*)d_in[2];  // [128,64]
    const float* bias  = (const float*)d_in[3];  // [128]
    const float* gamma = (const float*)d_in[4];  // [128]
    const float* beta  = (const float*)d_in[5];  // [128]
    float* out = (float*)d_out;

    // workspace carving (all 256B-aligned by construction)
    char* ws = (char*)d_ws;
    int*   fps_idx  = (int*)(ws);                          // 16*2048*4        = 131072 B
    int*   knn_idx  = (int*)(ws + 131072);                 // 16*2048*16*4     = 2097152 B
    float* partials = (float*)(ws + 131072 + 2097152);     // 2048*256*4       = 2097152 B
    float* stats    = (float*)(ws + 131072 + 2097152 + 2097152);        // 256*4 = 1024 B
    float* h        = (float*)(ws + 131072 + 2097152 + 2097152 + 1024); // 16*8192*128*4 = 64 MiB

    fps_kernel<<<B_, 1024, 0, stream>>>(xyz, fps_idx, out);   // also writes new_xyz
    knn_kernel<<<dim3(NPOINT / 16, B_), 1024, 0, stream>>>(xyz, fps_idx, knn_idx);
    gemm_kernel<<<(B_ * N_) / 64, 256, 0, stream>>>(feat, W, bias, h, partials);
    bn_finalize_kernel<<<COUT, 256, 0, stream>>>(partials, gamma, beta, stats);
    gather_max_kernel<<<(B_ * NPOINT) / 8, 256, 0, stream>>>(h, knn_idx, stats, out);
}